// Round 7
// baseline (77.023 us; speedup 1.0000x reference)
//
#include <hip/hip_runtime.h>
#include <hip/hip_fp16.h>
#include <math.h>

#define BB 64
#define TT 2000
#define VV 128
#define SS 100
#define NP 1000            // row-pairs per batch: pair p holds frames 2p+1, 2p+2
#define PRB 408            // bytes per pair-row: 51 lanes * 8B
#define LN2D 0.6931471805599453

// wave-wide f32 sum via DPP (VALU pipe, no LDS); result uniform via readlane
__device__ __forceinline__ float wave_sum_f32(float v) {
    int t;
    t = __builtin_amdgcn_update_dpp(0, __float_as_int(v), 0x111, 0xF, 0xF, true);  v += __int_as_float(t);
    t = __builtin_amdgcn_update_dpp(0, __float_as_int(v), 0x112, 0xF, 0xF, true);  v += __int_as_float(t);
    t = __builtin_amdgcn_update_dpp(0, __float_as_int(v), 0x114, 0xF, 0xF, true);  v += __int_as_float(t);
    t = __builtin_amdgcn_update_dpp(0, __float_as_int(v), 0x118, 0xF, 0xF, true);  v += __int_as_float(t);
    t = __builtin_amdgcn_update_dpp(0, __float_as_int(v), 0x142, 0xA, 0xF, false); v += __int_as_float(t); // bcast15
    t = __builtin_amdgcn_update_dpp(0, __float_as_int(v), 0x143, 0xC, 0xF, false); v += __int_as_float(t); // bcast31
    return __int_as_float(__builtin_amdgcn_readlane(__float_as_int(v), 63));
}

// ---------------- Kernel 1: blank-normalized label probs (unchanged, passing) ----------------
__global__ __launch_bounds__(256) void ctc_k1(
    const float* __restrict__ logits, const int* __restrict__ targets,
    ushort* __restrict__ pe2, float* __restrict__ logSb)
{
    const int wv = threadIdx.x >> 6, lane = threadIdx.x & 63;
    const int gp = blockIdx.x * 4 + wv;          // 0 .. BB*NP-1
    const int b = gp / NP, p = gp - b * NP;
    const int tA = 2 * p + 1, tB = 2 * p + 2;
    const bool vB = (tB < TT);

    const float2* rA = reinterpret_cast<const float2*>(logits + ((size_t)b * TT + tA) * VV);
    const float2* rB = reinterpret_cast<const float2*>(logits + ((size_t)b * TT + (vB ? tB : tA)) * VV);
    float2 xa = rA[lane], xb = rB[lane];

    float ea0 = __expf(xa.x), ea1 = __expf(xa.y);
    float eb0 = __expf(xb.x), eb1 = __expf(xb.y);
    float sa = wave_sum_f32(ea0 + ea1);
    float sb = wave_sum_f32(eb0 + eb1);

    __shared__ float sm[4][2][VV];
    sm[wv][0][2 * lane] = ea0; sm[wv][0][2 * lane + 1] = ea1;
    sm[wv][1][2 * lane] = eb0; sm[wv][1][2 * lane + 1] = eb1;
    // producer and consumer are the SAME wave: no barrier needed

    int tg0 = 0, tg1 = 0;
    if (lane < 50) {
        int2 tg = reinterpret_cast<const int2*>(targets)[b * (SS / 2) + lane];
        tg0 = tg.x; tg1 = tg.y;
    }
    const float qiA = 1.0f / sm[wv][0][0];
    const float qiB = 1.0f / sm[wv][1][0];
    float q1a = 0.f, q3a = 0.f, q1b = 0.f, q3b = 0.f;
    if (lane < 50) {
        q1a = fminf(sm[wv][0][tg0] * qiA, 65504.f);
        q3a = fminf(sm[wv][0][tg1] * qiA, 65504.f);
        if (vB) {
            q1b = fminf(sm[wv][1][tg0] * qiB, 65504.f);
            q3b = fminf(sm[wv][1][tg1] * qiB, 65504.f);
        }
    }
    if (lane < 51) {
        ushort4 w;
        w.x = __half_as_ushort(__float2half_rn(q1a));
        w.y = __half_as_ushort(__float2half_rn(q3a));
        w.z = __half_as_ushort(__float2half_rn(q1b));
        w.w = __half_as_ushort(__float2half_rn(q3b));
        *reinterpret_cast<ushort4*>((char*)pe2 + ((size_t)b * NP + p) * PRB + lane * 8) = w;
    }
    if (lane == 0) {
        logSb[b * TT + tA] = __logf(sa) - xa.x;
        if (vB) logSb[b * TT + tB] = __logf(sb) - xb.x;
    }
}

// ---------------- Kernel 2: bidirectional scan, 2 waves per batch ----------------
union H4 { uint2 u; __half h[4]; };

__device__ __forceinline__ double dpp_shr1_f64(double x) {   // lane l <- lane l-1, lane0 -> 0
    long long bl = __double_as_longlong(x);
    int lo = (int)bl, hi = (int)(bl >> 32);
    lo = __builtin_amdgcn_update_dpp(0, lo, 0x138, 0xF, 0xF, true);  // wave_shr:1
    hi = __builtin_amdgcn_update_dpp(0, hi, 0x138, 0xF, 0xF, true);
    return __longlong_as_double((long long)(((unsigned long long)(unsigned)hi << 32) | (unsigned)lo));
}

__device__ __forceinline__ double dpp_shl1_f64(double x) {   // lane l <- lane l+1, lane63 -> 0
    long long bl = __double_as_longlong(x);
    int lo = (int)bl, hi = (int)(bl >> 32);
    lo = __builtin_amdgcn_update_dpp(0, lo, 0x130, 0xF, 0xF, true);  // wave_shl:1
    hi = __builtin_amdgcn_update_dpp(0, hi, 0x130, 0xF, 0xF, true);
    return __longlong_as_double((long long)(((unsigned long long)(unsigned)hi << 32) | (unsigned)lo));
}

__device__ __forceinline__ int wave_max_i32(int v) {
    int t;
    t = __builtin_amdgcn_update_dpp(0, v, 0x111, 0xF, 0xF, true); v = v > t ? v : t;
    t = __builtin_amdgcn_update_dpp(0, v, 0x112, 0xF, 0xF, true); v = v > t ? v : t;
    t = __builtin_amdgcn_update_dpp(0, v, 0x114, 0xF, 0xF, true); v = v > t ? v : t;
    t = __builtin_amdgcn_update_dpp(0, v, 0x118, 0xF, 0xF, true); v = v > t ? v : t;
    t = __builtin_amdgcn_update_dpp(v, v, 0x142, 0xA, 0xF, false); v = v > t ? v : t;
    t = __builtin_amdgcn_update_dpp(v, v, 0x143, 0xC, 0xF, false); v = v > t ? v : t;
    return __builtin_amdgcn_readlane(v, 63);
}

// zero-out via bitmask (exact; values are nonneg, m is 0 or -1)
__device__ __forceinline__ double dand(double x, int m) {
    long long bl = __double_as_longlong(x);
    int lo = (int)bl & m, hi = (int)(bl >> 32) & m;
    return __longlong_as_double((long long)(((unsigned long long)(unsigned)hi << 32) | (unsigned)lo));
}

// Loop-carried state enters each update at the LAST fma (depth-1 recurrence).
// QkS = sk * Qk, precomputed in the cvt pipeline (off the a-chain).
#define FSTEP(Q1, Q1S, Q3, Q3S) do {                         \
    double am1 = dpp_shr1_f64(a3);                           \
    double n3 = fma(a3, (Q3), fma(a2, (Q3), a1 * (Q3S)));    \
    double n1 = fma(a1, (Q1), fma(a0, (Q1), am1 * (Q1S)));   \
    double n0 = a0 + am1;                                    \
    double n2 = a1 + a2;                                     \
    a0 = n0; a1 = n1; a2 = n2; a3 = n3;                      \
} while (0)

// bwd: Q1S = sk3*Q1 (slot 4l+1 <- 4l+3), Q3S = skB*Q3 (slot 4l+3 <- 4l+5)
#define BSTEP(Q1, Q1S, Q3, Q3S) do {                         \
    double bp0 = dpp_shl1_f64(a0);                           \
    double bp1 = dpp_shl1_f64(a1);                           \
    double c1 = fma(a1, (Q1), fma(a2, (Q1), a3 * (Q1S)));    \
    double c3 = fma(a3, (Q3), fma(bp0, (Q3), bp1 * (Q3S)));  \
    double c0 = a0 + a1;                                     \
    double c2 = a2 + a3;                                     \
    a0 = c0; a1 = c1; a2 = c2; a3 = c3;                      \
} while (0)

#define RENORM() do {                                        \
    int h0 = (int)(__double_as_longlong(a0) >> 32);          \
    int h1 = (int)(__double_as_longlong(a1) >> 32);          \
    int h2 = (int)(__double_as_longlong(a2) >> 32);          \
    int h3 = (int)(__double_as_longlong(a3) >> 32);          \
    int m01 = h0 > h1 ? h0 : h1;                             \
    int m23 = h2 > h3 ? h2 : h3;                             \
    int mm  = wave_max_i32(m01 > m23 ? m01 : m23);           \
    int ex  = (mm >> 20) & 0x7FF;                            \
    int exc = ex > 0 ? ex : 1;                               \
    double f = __longlong_as_double((long long)(2046 - exc) << 52); \
    a0 *= f; a1 *= f; a2 *= f; a3 *= f;                      \
    Epow += exc - 1023;                                      \
} while (0)

// fwd cvt: Q1S = sk1*Q1, Q3S = sk3*Q3  (mask-select, exact)
#define CVTF(H, Q1A,Q1SA,Q3A,Q3SA, Q1B,Q1SB,Q3B,Q3SB) do {   \
    Q1A = (double)__half2float((H).h[0]); Q1SA = dand(Q1A, mi1); \
    Q3A = (double)__half2float((H).h[1]); Q3SA = dand(Q3A, mi3); \
    Q1B = (double)__half2float((H).h[2]); Q1SB = dand(Q1B, mi1); \
    Q3B = (double)__half2float((H).h[3]); Q3SB = dand(Q3B, mi3); } while (0)

// bwd cvt: Q1S = sk3*Q1, Q3S = skB*Q3
#define CVTB(H, Q1A,Q1SA,Q3A,Q3SA, Q1B,Q1SB,Q3B,Q3SB) do {   \
    Q1A = (double)__half2float((H).h[0]); Q1SA = dand(Q1A, mi3); \
    Q3A = (double)__half2float((H).h[1]); Q3SA = dand(Q3A, miB); \
    Q1B = (double)__half2float((H).h[2]); Q1SB = dand(Q1B, mi3); \
    Q3B = (double)__half2float((H).h[3]); Q3SB = dand(Q3B, miB); } while (0)

__global__ __launch_bounds__(128) void ctc_k2(
    const float* __restrict__ logits, const ushort* __restrict__ pe2,
    const float* __restrict__ logSb, const int* __restrict__ targets,
    const int* __restrict__ in_lens, const int* __restrict__ tgt_lens,
    float* __restrict__ out)
{
    const int b    = blockIdx.x;
    const int tid  = threadIdx.x;
    const int wv   = tid >> 6;          // 0 = forward (alpha), 1 = backward (beta)
    const int lane = tid & 63;
    const int n    = in_lens[b];
    const int tl   = tgt_lens[b];

    const int P  = (13 * (n - 2)) / 50;     // forward pairs (frames 1..2P)
    const int pL = (n - 2) >> 1;            // pair containing frame n-1

    __shared__ double SA[256];
    __shared__ double SC[256];
    __shared__ double sred[2];
    __shared__ int    sE[2];

    // target-derived skip flags
    int tg0 = 0, tg1 = 0, tgm1 = 0, tg2 = 0;
    if (lane < 50) {
        int2 tg = reinterpret_cast<const int2*>(targets)[b * (SS / 2) + lane];
        tg0 = tg.x; tg1 = tg.y;
    }
    if (lane >= 1 && lane <= 50) tgm1 = targets[b * SS + 2 * lane - 1];
    if (lane <= 48) tg2 = targets[b * SS + 2 * lane + 2];
    const int mi1 = (tg0 != tgm1) ? -1 : 0;   // fwd: slot 4l+1 <- 4l-1
    const int mi3 = (tg1 != tg0)  ? -1 : 0;   // fwd: 4l+3 <- 4l+1; bwd: 4l+1 <- 4l+3
    const int miB = (tg2 != tg1)  ? -1 : 0;   // bwd: slot 4l+3 <- 4l+5
    const double sk3 = (tg1 != tg0) ? 1.0 : 0.0;
    const double skB = (tg2 != tg1) ? 1.0 : 0.0;

    const int cl = (lane < 51) ? lane : 50;
    const char* PBbase = (const char*)pe2 + (size_t)b * NP * PRB + (size_t)cl * 8;

    double a0 = 0.0, a1 = 0.0, a2 = 0.0, a3 = 0.0;
    int Epow = 0;
    double lsb0 = 0.0;
    uint2 buf[16];

    if (wv == 0) {
        // ---- frame 0 prologue from logits (register-only; no max-sub) ----
        float2 x0 = reinterpret_cast<const float2*>(logits + (size_t)b * TT * VV)[lane];
        float e00 = __expf(x0.x), e01 = __expf(x0.y);
        float s0v = wave_sum_f32(e00 + e01);
        float qb0 = __shfl(e00, 0);
        int ext1 = targets[b * SS];                      // first label (uniform)
        float qn = __shfl((ext1 & 1) ? e01 : e00, ext1 >> 1);
        if (lane == 0) {
            a0 = 1.0;
            if (tl > 0) a1 = (double)qn / (double)qb0;
            lsb0 = (double)__logf(s0v) - (double)x0.x;
        }

        // ---- forward pairs 0 .. P-1 (frames 1..2P), cvt pipelined 1 pair ahead ----
        #pragma unroll
        for (int d = 0; d < 16; ++d)
            buf[d] = *reinterpret_cast<const uint2*>(PBbase + (size_t)d * PRB);
        const char* Pc = PBbase + (size_t)16 * PRB;
        double c1A,c1sA,c3A,c3sA,c1B,c1sB,c3B,c3sB;
        double n1A,n1sA,n3A,n3sA,n1B,n1sB,n3B,n3sB;
        { H4 h0; h0.u = buf[0]; CVTF(h0, c1A,c1sA,c3A,c3sA, c1B,c1sB,c3B,c3sB); }
        const int nfull = P >> 4, rem = P & 15;
        for (int c = 0; c < nfull; ++c) {
            #pragma unroll
            for (int d = 0; d < 16; ++d) {
                H4 hn; hn.u = buf[(d + 1) & 15];
                buf[d] = *reinterpret_cast<const uint2*>(Pc + (size_t)d * PRB);
                CVTF(hn, n1A,n1sA,n3A,n3sA, n1B,n1sB,n3B,n3sB);
                FSTEP(c1A, c1sA, c3A, c3sA);
                FSTEP(c1B, c1sB, c3B, c3sB);
                c1A=n1A; c1sA=n1sA; c3A=n3A; c3sA=n3sA;
                c1B=n1B; c1sB=n1sB; c3B=n3B; c3sB=n3sB;
            }
            RENORM();
            Pc += (size_t)16 * PRB;
        }
        #pragma unroll
        for (int d = 0; d < 16; ++d) {
            if (d < rem) {
                H4 h; h.u = buf[d];
                double q1A,q1sA,q3A,q3sA,q1B,q1sB,q3B,q3sB;
                CVTF(h, q1A,q1sA,q3A,q3sA, q1B,q1sB,q3B,q3sB);
                FSTEP(q1A, q1sA, q3A, q3sA);
                FSTEP(q1B, q1sB, q3B, q3sB);
            }
        }
        RENORM();
        SA[4 * lane + 0] = a0; SA[4 * lane + 1] = a1;
        SA[4 * lane + 2] = a2; SA[4 * lane + 3] = a3;
        if (lane == 0) sE[0] = Epow;
    } else {
        // ---- backward init at frame n-1 (from pair pL) ----
        H4 hi; hi.u = *reinterpret_cast<const uint2*>(PBbase + (size_t)pL * PRB);
        const bool nOdd = (n & 1);
        double q1i = (double)__half2float(nOdd ? hi.h[2] : hi.h[0]);
        double q3i = (double)__half2float(nOdd ? hi.h[3] : hi.h[1]);
        const int s2 = 2 * tl, s1 = 2 * tl - 1;
        a0 = (4 * lane     == s2) ? 1.0 : 0.0;
        a1 = (4 * lane + 1 == s1) ? q1i : 0.0;
        a2 = (4 * lane + 2 == s2) ? 1.0 : 0.0;
        a3 = (4 * lane + 3 == s1) ? q3i : 0.0;
        if (nOdd) {   // extra step for frame n-2 = tA of pair pL
            double q1 = (double)__half2float(hi.h[0]);
            double q3 = (double)__half2float(hi.h[1]);
            double q1s = dand(q1, mi3), q3s = dand(q3, miB);
            BSTEP(q1, q1s, q3, q3s);
        }

        // ---- backward pairs pL-1 down to P (frames 2pL .. 2P+1), cvt pipelined ----
        const int NB = pL - P;
        #pragma unroll
        for (int d = 0; d < 16; ++d)
            buf[d] = *reinterpret_cast<const uint2*>(PBbase + (size_t)(pL - 1 - d) * PRB);
        const char* Pc = PBbase + (size_t)(pL - 1 - 16) * PRB;
        double c1A,c1sA,c3A,c3sA,c1B,c1sB,c3B,c3sB;
        double n1A,n1sA,n3A,n3sA,n1B,n1sB,n3B,n3sB;
        { H4 h0; h0.u = buf[0]; CVTB(h0, c1A,c1sA,c3A,c3sA, c1B,c1sB,c3B,c3sB); }
        const int nfull = NB >> 4, rem = NB & 15;
        for (int c = 0; c < nfull; ++c) {
            #pragma unroll
            for (int d = 0; d < 16; ++d) {
                H4 hn; hn.u = buf[(d + 1) & 15];
                buf[d] = *reinterpret_cast<const uint2*>(Pc - (size_t)d * PRB);
                CVTB(hn, n1A,n1sA,n3A,n3sA, n1B,n1sB,n3B,n3sB);
                BSTEP(c1B, c1sB, c3B, c3sB);     // frame tB first (higher t)
                BSTEP(c1A, c1sA, c3A, c3sA);
                c1A=n1A; c1sA=n1sA; c3A=n3A; c3sA=n3sA;
                c1B=n1B; c1sB=n1sB; c3B=n3B; c3sB=n3sB;
            }
            RENORM();
            Pc -= (size_t)16 * PRB;
        }
        #pragma unroll
        for (int d = 0; d < 16; ++d) {
            if (d < rem) {
                H4 h; h.u = buf[d];
                double q1A,q1sA,q3A,q3sA,q1B,q1sB,q3B,q3sB;
                CVTB(h, q1A,q1sA,q3A,q3sA, q1B,q1sB,q3B,q3sB);
                BSTEP(q1B, q1sB, q3B, q3sB);
                BSTEP(q1A, q1sA, q3A, q3sA);
            }
        }
        RENORM();
        // final shift-add (no q): C = betaX at frame 2P
        {
            double bp0 = dpp_shl1_f64(a0);
            double bp1 = dpp_shl1_f64(a1);
            double c0 = a0 + a1;
            double c1 = fma(sk3, a3, a1 + a2);
            double c2 = a2 + a3;
            double c3 = fma(skB, bp1, a3 + bp0);
            SC[4 * lane + 0] = c0; SC[4 * lane + 1] = c1;
            SC[4 * lane + 2] = c2; SC[4 * lane + 3] = c3;
        }
        if (lane == 0) sE[1] = Epow;
    }

    // logSb partial sums over frames 1..n-1, strided across all 128 threads
    double cb = 0.0;
    for (int t = 1 + tid; t < n; t += 128) cb += (double)logSb[b * TT + t];
    #pragma unroll
    for (int off = 32; off; off >>= 1) cb += __shfl_xor(cb, off);
    if (lane == 0) sred[wv] = cb;

    __syncthreads();

    if (wv == 0) {
        double d0 = SA[4 * lane + 0] * SC[4 * lane + 0]
                  + SA[4 * lane + 1] * SC[4 * lane + 1]
                  + SA[4 * lane + 2] * SC[4 * lane + 2]
                  + SA[4 * lane + 3] * SC[4 * lane + 3];
        #pragma unroll
        for (int off = 32; off; off >>= 1) d0 += __shfl_xor(d0, off);
        if (lane == 0) {
            double dot = d0;
            int extraE = 0;
            long long bits = __double_as_longlong(dot);
            int be = (int)((bits >> 52) & 0x7FF);
            if (be == 0) {                 // denormal rescue
                dot *= 0x1.0p+512;
                bits = __double_as_longlong(dot);
                be = (int)((bits >> 52) & 0x7FF);
                extraE = -512;
            }
            double mant = __longlong_as_double((bits & 0xFFFFFFFFFFFFFLL) | 0x3FF0000000000000LL);
            double logdot = ((double)(be - 1023 + extraE + sE[0] + sE[1])) * LN2D
                          + (double)__logf((float)mant);
            double loss = (sred[0] + sred[1] + lsb0) - logdot;
            atomicAdd(out, (float)loss);
        }
    }
}

extern "C" void kernel_launch(void* const* d_in, const int* in_sizes, int n_in,
                              void* d_out, int out_size, void* d_ws, size_t ws_size,
                              hipStream_t stream)
{
    const float* logits  = (const float*)d_in[0];
    const int* targets   = (const int*)d_in[1];
    const int* in_lens   = (const int*)d_in[2];
    const int* tgt_lens  = (const int*)d_in[3];
    float* out = (float*)d_out;

    ushort* pe2 = (ushort*)d_ws;
    float* logSb = (float*)((char*)d_ws + (size_t)BB * NP * PRB);

    hipMemsetAsync(d_out, 0, sizeof(float), stream);
    ctc_k1<<<BB * NP / 4, 256, 0, stream>>>(logits, targets, pe2, logSb);
    ctc_k2<<<BB, 128, 0, stream>>>(logits, pe2, logSb, targets, in_lens, tgt_lens, out);
}